// Round 3
// baseline (2286.765 us; speedup 1.0000x reference)
//
#include <hip/hip_runtime.h>
#include <hip/hip_bf16.h>

// CGCNN: 3x CGConv + projection + mean-pool + 2-layer MLP.
// Round 9: fuse aggregation into edge_msg via run-length-reduced atomicAdd
// directly into h (kills the 410MB bf16 message buffer write + 410MB read +
// agg_sum kernel; messages stay f32). LDS row stride 16->20 dwords to break
// the 8-way ds_read_b128 bank conflict (1.28e7 conflict cycles/dispatch).
// Biases folded into Pb dst gates at node_gemm2 pack time.

#define N_NODES 100000
#define N_EDGES 1600000
#define HID 128
#define SCAN_BLOCKS 391  // ceil(100000/256)

typedef unsigned int uint;
typedef short bf16x8 __attribute__((ext_vector_type(8)));
typedef float f32x4 __attribute__((ext_vector_type(4)));

__device__ inline float bflo(uint u) { return __uint_as_float(u << 16); }
__device__ inline float bfhi(uint u) { return __uint_as_float(u & 0xffff0000u); }
__device__ inline uint pack_bf16_2(float a, float b) {
  uint ua = __float_as_uint(a), ub = __float_as_uint(b);
  ua = (ua + 0x7fffu + ((ua >> 16) & 1u)) >> 16;
  ub = (ub + 0x7fffu + ((ub >> 16) & 1u)) >> 16;
  return ua | (ub << 16);
}
__device__ inline float sigmoidf_(float x) {
  return __builtin_amdgcn_rcpf(1.f + __expf(-x));
}
__device__ inline float softplusf_(float x) {
  return fmaxf(x, 0.f) + __logf(1.f + __expf(-fabsf(x)));
}

// ---------------- CSR build ----------------
__global__ __launch_bounds__(256) void hist_k(const int* __restrict__ ei,
                                              int* __restrict__ deg) {
  int e = blockIdx.x * 256 + threadIdx.x;
  if (e >= N_EDGES) return;
  atomicAdd(&deg[ei[N_EDGES + e]], 1);
}

__global__ __launch_bounds__(256) void scan1_k(const int* __restrict__ deg,
                                               int* __restrict__ rowptr,
                                               int* __restrict__ bsums) {
  __shared__ int s[256];
  int i = blockIdx.x * 256 + threadIdx.x;
  int v = (i < N_NODES) ? deg[i] : 0;
  s[threadIdx.x] = v;
  __syncthreads();
  for (int off = 1; off < 256; off <<= 1) {
    int t = (threadIdx.x >= off) ? s[threadIdx.x - off] : 0;
    __syncthreads();
    s[threadIdx.x] += t;
    __syncthreads();
  }
  if (i < N_NODES) rowptr[i] = s[threadIdx.x] - v;  // exclusive
  if (threadIdx.x == 255) bsums[blockIdx.x] = s[255];
}

__global__ __launch_bounds__(512) void scan2_k(int* __restrict__ bsums) {
  __shared__ int s[512];
  int t = threadIdx.x;
  int v = (t < SCAN_BLOCKS) ? bsums[t] : 0;
  s[t] = v;
  __syncthreads();
  for (int off = 1; off < 512; off <<= 1) {
    int x = (t >= off) ? s[t - off] : 0;
    __syncthreads();
    s[t] += x;
    __syncthreads();
  }
  if (t < SCAN_BLOCKS) bsums[t] = s[t] - v;  // exclusive
}

__global__ __launch_bounds__(256) void scan3_k(int* __restrict__ rowptr,
                                               const int* __restrict__ bsums,
                                               int* __restrict__ cur) {
  int i = blockIdx.x * 256 + threadIdx.x;
  if (i < N_NODES) {
    int r = rowptr[i] + bsums[blockIdx.x];
    rowptr[i] = r;
    cur[i] = r;
  }
  if (i == 0) rowptr[N_NODES] = N_EDGES;
}

// csr entry: {src, e, dst, 0}
__global__ __launch_bounds__(256) void scatter_k(const int* __restrict__ ei,
                                                 int* __restrict__ cur,
                                                 uint4* __restrict__ csr) {
  int e = blockIdx.x * 256 + threadIdx.x;
  if (e >= N_EDGES) return;
  int d = ei[N_EDGES + e];
  int pos = atomicAdd(&cur[d], 1);
  csr[pos] = make_uint4((uint)ei[e], (uint)e, (uint)d, 0u);
}

// ---------------- conv1 (channels=3) ----------------
__global__ __launch_bounds__(256) void conv1_edge(
    const float* __restrict__ x, const int* __restrict__ ei,
    const float* __restrict__ ea,
    const float* __restrict__ Wf, const float* __restrict__ bf,
    const float* __restrict__ Ws, const float* __restrict__ bs,
    float* __restrict__ agg1) {
  int e = blockIdx.x * 256 + threadIdx.x;
  if (e >= N_EDGES) return;
  int src = ei[e], dst = ei[N_EDGES + e];
  float z[38];
#pragma unroll
  for (int k = 0; k < 3; ++k) z[k] = x[dst * 3 + k];
#pragma unroll
  for (int k = 0; k < 3; ++k) z[3 + k] = x[src * 3 + k];
  const float4* er4 = (const float4*)(ea + (long long)e * 32);
#pragma unroll
  for (int k = 0; k < 8; ++k) {
    float4 v = er4[k];
    z[6 + 4 * k + 0] = v.x;
    z[6 + 4 * k + 1] = v.y;
    z[6 + 4 * k + 2] = v.z;
    z[6 + 4 * k + 3] = v.w;
  }
#pragma unroll
  for (int c = 0; c < 3; ++c) {
    float f = bf[c], s = bs[c];
#pragma unroll
    for (int k = 0; k < 38; ++k) {
      f = fmaf(z[k], Wf[k * 3 + c], f);
      s = fmaf(z[k], Ws[k * 3 + c], s);
    }
    atomicAdd(&agg1[dst * 3 + c], sigmoidf_(f) * softplusf_(s));
  }
}

// ---------------- projection: h = relu((x+agg1) @ Wp + bp) ----------------
__global__ __launch_bounds__(256) void proj_kernel(
    const float* __restrict__ x, const float* __restrict__ agg1,
    const float* __restrict__ Wp, const float* __restrict__ bp,
    float* __restrict__ h) {
  long long i = (long long)blockIdx.x * 256 + threadIdx.x;
  if (i >= (long long)N_NODES * HID) return;
  int n = (int)(i >> 7), j = (int)(i & 127);
  float v0 = x[n * 3 + 0] + agg1[n * 3 + 0];
  float v1 = x[n * 3 + 1] + agg1[n * 3 + 1];
  float v2 = x[n * 3 + 2] + agg1[n * 3 + 2];
  float acc = bp[j];
  acc = fmaf(v0, Wp[0 * HID + j], acc);
  acc = fmaf(v1, Wp[1 * HID + j], acc);
  acc = fmaf(v2, Wp[2 * HID + j], acc);
  h[i] = fmaxf(acc, 0.f);
}

#define BM 64
#define BK 32

// ---------------- node gates, packed {f,s} per channel ----------------
// Pb[node][256 dwords]: [0..127] = {f_dst+bf, s_dst+bs} per ch (biases
// folded here, once per edge via the dst gate); [128..255] = {f_src, s_src}
__global__ __launch_bounds__(256) void node_gemm2(
    const float* __restrict__ h, const float* __restrict__ Wf,
    const float* __restrict__ Ws, const float* __restrict__ bf,
    const float* __restrict__ bs, uint* __restrict__ Pb) {
  __shared__ float As[BK][BM + 4];
  __shared__ float BfS[BK][BM + 4];
  __shared__ float BsS[BK][BM + 4];
  int jblk = blockIdx.x;            // 0..3
  int part = jblk >> 1;             // 0 dst, 1 src
  int colbase = (jblk & 1) * 64;
  int rowoff = part * 128;
  int m0 = blockIdx.y * BM;
  int tid = threadIdx.x, tx = tid & 15, ty = tid >> 4;
  float accF[4][4] = {}, accS[4][4] = {};
  for (int k0 = 0; k0 < 128; k0 += BK) {
#pragma unroll
    for (int i = 0; i < 2; ++i) {
      int f = tid + i * 256;
      int r = f >> 3, c4 = (f & 7) * 4;
      float4 v = {0.f, 0.f, 0.f, 0.f};
      int row = m0 + r;
      if (row < N_NODES)
        v = *(const float4*)&h[(long long)row * 128 + k0 + c4];
      As[c4 + 0][r] = v.x; As[c4 + 1][r] = v.y;
      As[c4 + 2][r] = v.z; As[c4 + 3][r] = v.w;
    }
#pragma unroll
    for (int i = 0; i < 2; ++i) {
      int f = tid + i * 256;
      int r = f >> 4, c4 = (f & 15) * 4;
      *(float4*)&BfS[r][c4] =
          *(const float4*)&Wf[(long long)(k0 + r + rowoff) * 128 + colbase + c4];
      *(float4*)&BsS[r][c4] =
          *(const float4*)&Ws[(long long)(k0 + r + rowoff) * 128 + colbase + c4];
    }
    __syncthreads();
#pragma unroll
    for (int k = 0; k < BK; ++k) {
      float4 a = *(const float4*)&As[k][ty * 4];
      float4 bF = *(const float4*)&BfS[k][tx * 4];
      float4 bS = *(const float4*)&BsS[k][tx * 4];
      float av[4] = {a.x, a.y, a.z, a.w};
      float bFv[4] = {bF.x, bF.y, bF.z, bF.w};
      float bSv[4] = {bS.x, bS.y, bS.z, bS.w};
#pragma unroll
      for (int i = 0; i < 4; ++i)
#pragma unroll
        for (int j = 0; j < 4; ++j) {
          accF[i][j] = fmaf(av[i], bFv[j], accF[i][j]);
          accS[i][j] = fmaf(av[i], bSv[j], accS[i][j]);
        }
    }
    __syncthreads();
  }
  float fbias[4] = {0.f, 0.f, 0.f, 0.f}, sbias[4] = {0.f, 0.f, 0.f, 0.f};
  if (part == 0) {
#pragma unroll
    for (int j = 0; j < 4; ++j) {
      fbias[j] = bf[colbase + tx * 4 + j];
      sbias[j] = bs[colbase + tx * 4 + j];
    }
  }
#pragma unroll
  for (int i = 0; i < 4; ++i) {
    int row = m0 + ty * 4 + i;
    if (row < N_NODES) {
      uint4 o;
      o.x = pack_bf16_2(accF[i][0] + fbias[0], accS[i][0] + sbias[0]);
      o.y = pack_bf16_2(accF[i][1] + fbias[1], accS[i][1] + sbias[1]);
      o.z = pack_bf16_2(accF[i][2] + fbias[2], accS[i][2] + sbias[2]);
      o.w = pack_bf16_2(accF[i][3] + fbias[3], accS[i][3] + sbias[3]);
      *(uint4*)&Pb[(long long)row * 256 + part * 128 + colbase + tx * 4] = o;
    }
  }
}

// ---- w_prep: Btg[ch 0..255][16 dwords] = bf16{W[256+2k][c], W[256+2k+1][c]} ----
// ch 0..127 -> Wf columns (f), 128..255 -> Ws columns (s). One block.
__global__ __launch_bounds__(256) void w_prep(const float* __restrict__ Wf,
                                              const float* __restrict__ Ws,
                                              uint* __restrict__ Btg) {
  int t = threadIdx.x;
  const float* W = (t < 128) ? Wf : Ws;
  int c = t & 127;
#pragma unroll
  for (int kk = 0; kk < 16; ++kk) {
    float a = W[(256 + 2 * kk) * 128 + c];
    float b = W[(256 + 2 * kk + 1) * 128 + c];
    Btg[t * 16 + kk] = pack_bf16_2(a, b);
  }
}

// ---- edge_msg: MFMA edge-gemm + gates + activations + fused CSR-run
//      aggregation via atomicAdd into h (f32 messages, no intermediate) ----
#define EMSG_EB 64
#define LSTR 20  // LDS row stride in dwords: 80B keeps b128 alignment,
                 // spreads 16-lane b128 groups over 8 bank-quads (2-way=free)
__global__ __launch_bounds__(256, 4) void edge_msg(
    const uint* __restrict__ Pb, const float* __restrict__ ea,
    const uint* __restrict__ Btg, const uint4* __restrict__ csr,
    float* __restrict__ h) {
  __shared__ uint Alds[EMSG_EB * LSTR];   // [edge][16 used dwords]
  __shared__ uint Blds[256 * LSTR];       // [ch][16 used dwords]
  int tid = threadIdx.x;
  int j0 = blockIdx.x * EMSG_EB;
  // stage B (weights, bf16 k-pairs)
  {
    const uint4* s4 = (const uint4*)(Btg + tid * 16);
    uint4 v0 = s4[0], v1 = s4[1], v2 = s4[2], v3 = s4[3];
    uint* d = &Blds[tid * LSTR];
    *(uint4*)(d + 0) = v0; *(uint4*)(d + 4) = v1;
    *(uint4*)(d + 8) = v2; *(uint4*)(d + 12) = v3;
  }
  // stage A: 4 threads per edge row, 8 floats each -> bf16 pairs
  {
    int r = tid >> 2, q = tid & 3;
    uint e = csr[j0 + r].y;
    const float4* er = (const float4*)(ea + (long long)e * 32 + q * 8);
    float4 a0 = er[0], a1 = er[1];
    uint4 pk;
    pk.x = pack_bf16_2(a0.x, a0.y);
    pk.y = pack_bf16_2(a0.z, a0.w);
    pk.z = pack_bf16_2(a1.x, a1.y);
    pk.w = pack_bf16_2(a1.z, a1.w);
    *(uint4*)&Alds[r * LSTR + q * 4] = pk;
  }
  __syncthreads();
  int wave = tid >> 6, lane = tid & 63;
  int c0w = wave * 32;           // 32 channels per wave
  int l15 = lane & 15, lq = lane >> 4;
  bf16x8 afr[4], bfr[4];
#pragma unroll
  for (int mt = 0; mt < 4; ++mt)
    afr[mt] = *(const bf16x8*)&Alds[(mt * 16 + l15) * LSTR + lq * 4];
  int chs0 = c0w + l15, chs1 = c0w + 16 + l15;
  bfr[0] = *(const bf16x8*)&Blds[chs0 * LSTR + lq * 4];
  bfr[1] = *(const bf16x8*)&Blds[chs1 * LSTR + lq * 4];
  bfr[2] = *(const bf16x8*)&Blds[(128 + chs0) * LSTR + lq * 4];
  bfr[3] = *(const bf16x8*)&Blds[(128 + chs1) * LSTR + lq * 4];
  f32x4 acc[4][4];
#pragma unroll
  for (int mt = 0; mt < 4; ++mt)
#pragma unroll
    for (int nt = 0; nt < 4; ++nt) {
      f32x4 z = {0.f, 0.f, 0.f, 0.f};
      acc[mt][nt] = __builtin_amdgcn_mfma_f32_16x16x32_bf16(afr[mt], bfr[nt], z, 0, 0, 0);
    }
  // epilogue: C layout col=lane&15 (ch), row=(lane>>4)*4+reg (edge).
  // Each 16-lane group owns 4 CSR-consecutive edges -> run-length reduce
  // over equal dst, one atomicAdd per run directly into h.
#pragma unroll
  for (int mt = 0; mt < 4; ++mt) {
    int jb = j0 + mt * 16 + lq * 4;
    uint srcs[4], dsts[4];
#pragma unroll
    for (int reg = 0; reg < 4; ++reg) {
      uint4 cj = csr[jb + reg];
      srcs[reg] = cj.x;
      dsts[reg] = cj.z;
    }
#pragma unroll
    for (int cp = 0; cp < 2; ++cp) {
      int c = (cp ? chs1 : chs0);
      float mr[4];
#pragma unroll
      for (int reg = 0; reg < 4; ++reg) {
        uint gd = Pb[(long long)dsts[reg] * 256 + c];
        uint gs = Pb[(long long)srcs[reg] * 256 + 128 + c];
        float f = acc[mt][cp][reg] + bflo(gd) + bflo(gs);
        float s = acc[mt][2 + cp][reg] + bfhi(gd) + bfhi(gs);
        mr[reg] = sigmoidf_(f) * softplusf_(s);
      }
      float racc = mr[0];
#pragma unroll
      for (int reg = 1; reg < 4; ++reg) {
        if (dsts[reg] == dsts[reg - 1]) {
          racc += mr[reg];
        } else {
          atomicAdd(&h[(long long)dsts[reg - 1] * HID + c], racc);
          racc = mr[reg];
        }
      }
      atomicAdd(&h[(long long)dsts[3] * HID + c], racc);
    }
  }
}

// ---- relu in place over h ----
__global__ __launch_bounds__(256) void relu_k(float* __restrict__ h) {
  const int total = N_NODES * HID / 4;
  for (int i = blockIdx.x * 256 + threadIdx.x; i < total; i += gridDim.x * 256) {
    float4 v = ((float4*)h)[i];
    v.x = fmaxf(v.x, 0.f); v.y = fmaxf(v.y, 0.f);
    v.z = fmaxf(v.z, 0.f); v.w = fmaxf(v.w, 0.f);
    ((float4*)h)[i] = v;
  }
}

// -------- segmented mean pool (batch sorted) --------
#define POOL_NODES 128
__global__ __launch_bounds__(128) void pool2(
    const float* __restrict__ h, const int* __restrict__ batch,
    float* __restrict__ sums, float* __restrict__ cnts) {
  int n0 = blockIdx.x * POOL_NODES;
  if (n0 >= N_NODES) return;
  int t = threadIdx.x;
  int nEnd = n0 + POOL_NODES;
  if (nEnd > N_NODES) nEnd = N_NODES;
  float acc = 0.f;
  int bcur = batch[n0];
  int cnt = 0;
  for (int n = n0; n < nEnd; ++n) {
    int b = batch[n];
    if (b != bcur) {
      atomicAdd(&sums[bcur * HID + t], acc);
      if (t == 0) atomicAdd(&cnts[bcur], (float)cnt);
      acc = 0.f; cnt = 0; bcur = b;
    }
    acc += h[(long long)n * HID + t];
    ++cnt;
  }
  atomicAdd(&sums[bcur * HID + t], acc);
  if (t == 0) atomicAdd(&cnts[bcur], (float)cnt);
}

// ---------------- graph MLP ----------------
__global__ __launch_bounds__(128) void mlpA(
    const float* __restrict__ sums, const float* __restrict__ cnts,
    const float* __restrict__ W1, const float* __restrict__ b1,
    float* __restrict__ g) {
  __shared__ float pl[HID];
  int gr = blockIdx.x, j = threadIdx.x;
  float cnt = fmaxf(cnts[gr], 1.f);
  pl[j] = sums[gr * HID + j] / cnt;
  __syncthreads();
  float acc = b1[j];
#pragma unroll 8
  for (int k = 0; k < HID; ++k) acc = fmaf(pl[k], W1[k * HID + j], acc);
  g[gr * HID + j] = fmaxf(acc, 0.f);
}

__global__ __launch_bounds__(256) void mlpB(
    const float* __restrict__ g, const float* __restrict__ W2,
    const float* __restrict__ b2, float* __restrict__ out) {
  int t = threadIdx.x;
  if (t >= 64 * 3) return;
  int gr = t / 3, o = t % 3;
  float acc = b2[o];
#pragma unroll 8
  for (int k = 0; k < HID; ++k) acc = fmaf(g[gr * HID + k], W2[k * 3 + o], acc);
  out[t] = acc;
}

extern "C" void kernel_launch(void* const* d_in, const int* in_sizes, int n_in,
                              void* d_out, int out_size, void* d_ws, size_t ws_size,
                              hipStream_t stream) {
  const float* x   = (const float*)d_in[0];
  const int*   ei  = (const int*)d_in[1];
  const float* ea  = (const float*)d_in[2];
  const int*   bat = (const int*)d_in[3];
  const float* Wf1 = (const float*)d_in[4];
  const float* bf1 = (const float*)d_in[5];
  const float* Ws1 = (const float*)d_in[6];
  const float* bs1 = (const float*)d_in[7];
  const float* Wp  = (const float*)d_in[8];
  const float* bp  = (const float*)d_in[9];
  const float* Wf2 = (const float*)d_in[10];
  const float* bf2 = (const float*)d_in[11];
  const float* Ws2 = (const float*)d_in[12];
  const float* bs2 = (const float*)d_in[13];
  const float* Wf3 = (const float*)d_in[14];
  const float* bf3 = (const float*)d_in[15];
  const float* Ws3 = (const float*)d_in[16];
  const float* bs3 = (const float*)d_in[17];
  const float* W1  = (const float*)d_in[18];
  const float* b1  = (const float*)d_in[19];
  const float* W2  = (const float*)d_in[20];
  const float* b2  = (const float*)d_in[21];
  float* out = (float*)d_out;

  char* w = (char*)d_ws;
  size_t off = 0;
  auto alloc = [&](size_t bytes) {
    void* p = w + off;
    off += (bytes + 255) & ~(size_t)255;
    return p;
  };
  int*   deg    = (int*)alloc((size_t)N_NODES * 4);
  int*   rowptr = (int*)alloc((size_t)(N_NODES + 1) * 4);
  int*   cur    = (int*)alloc((size_t)N_NODES * 4);
  int*   bsums  = (int*)alloc((size_t)512 * 4);
  uint4* csr    = (uint4*)alloc((size_t)N_EDGES * 16);       // 25.6 MB
  float* agg1   = (float*)alloc((size_t)N_NODES * 3 * 4);    // 1.2 MB
  float* h      = (float*)alloc((size_t)N_NODES * HID * 4);  // 51.2 MB
  uint*  Pb     = (uint*)alloc((size_t)N_NODES * 256 * 4);   // 102.4 MB
  float* sums   = (float*)alloc((size_t)64 * HID * 4);
  float* cnts   = (float*)alloc((size_t)64 * 4);
  float* g      = (float*)alloc((size_t)64 * HID * 4);
  uint*  Btg    = (uint*)alloc((size_t)256 * 16 * 4);        // 16 KB
  (void)ws_size;  // total ~182 MB

  // ---- CSR build ----
  hipMemsetAsync(deg, 0, (size_t)N_NODES * 4, stream);
  hist_k<<<(N_EDGES + 255) / 256, 256, 0, stream>>>(ei, deg);
  scan1_k<<<SCAN_BLOCKS, 256, 0, stream>>>(deg, rowptr, bsums);
  scan2_k<<<1, 512, 0, stream>>>(bsums);
  scan3_k<<<SCAN_BLOCKS, 256, 0, stream>>>(rowptr, bsums, cur);
  scatter_k<<<(N_EDGES + 255) / 256, 256, 0, stream>>>(ei, cur, csr);

  // ---- conv1 ----
  hipMemsetAsync(agg1, 0, (size_t)N_NODES * 3 * 4, stream);
  conv1_edge<<<(N_EDGES + 255) / 256, 256, 0, stream>>>(x, ei, ea, Wf1, bf1, Ws1, bs1, agg1);
  proj_kernel<<<(N_NODES * HID + 255) / 256, 256, 0, stream>>>(x, agg1, Wp, bp, h);

  dim3 ngrid2(4, (N_NODES + BM - 1) / BM);
  int eblocks = N_EDGES / EMSG_EB;  // 25000, exact

  // ---- conv2: h += agg (atomic), then relu in place ----
  node_gemm2<<<ngrid2, 256, 0, stream>>>(h, Wf2, Ws2, bf2, bs2, Pb);
  w_prep<<<1, 256, 0, stream>>>(Wf2, Ws2, Btg);
  edge_msg<<<eblocks, 256, 0, stream>>>(Pb, ea, Btg, csr, h);
  relu_k<<<4096, 256, 0, stream>>>(h);

  // ---- conv3 ----
  node_gemm2<<<ngrid2, 256, 0, stream>>>(h, Wf3, Ws3, bf3, bs3, Pb);
  w_prep<<<1, 256, 0, stream>>>(Wf3, Ws3, Btg);
  edge_msg<<<eblocks, 256, 0, stream>>>(Pb, ea, Btg, csr, h);
  relu_k<<<4096, 256, 0, stream>>>(h);

  // ---- pool + MLP ----
  hipMemsetAsync(sums, 0, (size_t)(64 * HID + 64) * 4, stream);
  pool2<<<(N_NODES + POOL_NODES - 1) / POOL_NODES, POOL_NODES, 0, stream>>>(h, bat, sums, cnts);
  mlpA<<<64, 128, 0, stream>>>(sums, cnts, W1, b1, g);
  mlpB<<<1, 256, 0, stream>>>(g, W2, b2, out);
}

// Round 4
// 2038.280 us; speedup vs baseline: 1.1219x; 1.1219x over previous
//
#include <hip/hip_runtime.h>
#include <hip/hip_bf16.h>

// CGCNN: 3x CGConv + projection + mean-pool + 2-layer MLP.
// Round 10: fused aggregation without the 61M global-atomic storm (Round 9's
// regression: atomic-throughput-bound at ~100G dword-atomics/s):
//   - per-block LDS accumulator keyed by local dst index (<=16 distinct dsts
//     per 64-edge CSR window; register run-reduce -> LDS atomicAdd)
//   - rowptr completeness check: nodes fully contained in the window are
//     flushed with a plain RMW h=relu(h+agg) (block owns them exclusively);
//     only the <=2 straddling nodes per window use global atomicAdd (~6.4M)
//   - ea pre-packed to bf16 in CSR order ONCE (ea_pack, reused by conv2&3):
//     stage-A is a coalesced 4KB copy; -100MB fetch/layer; no per-layer pack
//   - relu_k after each layer (idempotent on interior nodes, finishes
//     straddlers and degree-0 nodes)

#define N_NODES 100000
#define N_EDGES 1600000
#define HID 128
#define SCAN_BLOCKS 391  // ceil(100000/256)

typedef unsigned int uint;
typedef short bf16x8 __attribute__((ext_vector_type(8)));
typedef float f32x4 __attribute__((ext_vector_type(4)));

__device__ inline float bflo(uint u) { return __uint_as_float(u << 16); }
__device__ inline float bfhi(uint u) { return __uint_as_float(u & 0xffff0000u); }
__device__ inline uint pack_bf16_2(float a, float b) {
  uint ua = __float_as_uint(a), ub = __float_as_uint(b);
  ua = (ua + 0x7fffu + ((ua >> 16) & 1u)) >> 16;
  ub = (ub + 0x7fffu + ((ub >> 16) & 1u)) >> 16;
  return ua | (ub << 16);
}
__device__ inline float sigmoidf_(float x) {
  return __builtin_amdgcn_rcpf(1.f + __expf(-x));
}
__device__ inline float softplusf_(float x) {
  return fmaxf(x, 0.f) + __logf(1.f + __expf(-fabsf(x)));
}

// ---------------- CSR build ----------------
__global__ __launch_bounds__(256) void hist_k(const int* __restrict__ ei,
                                              int* __restrict__ deg) {
  int e = blockIdx.x * 256 + threadIdx.x;
  if (e >= N_EDGES) return;
  atomicAdd(&deg[ei[N_EDGES + e]], 1);
}

__global__ __launch_bounds__(256) void scan1_k(const int* __restrict__ deg,
                                               int* __restrict__ rowptr,
                                               int* __restrict__ bsums) {
  __shared__ int s[256];
  int i = blockIdx.x * 256 + threadIdx.x;
  int v = (i < N_NODES) ? deg[i] : 0;
  s[threadIdx.x] = v;
  __syncthreads();
  for (int off = 1; off < 256; off <<= 1) {
    int t = (threadIdx.x >= off) ? s[threadIdx.x - off] : 0;
    __syncthreads();
    s[threadIdx.x] += t;
    __syncthreads();
  }
  if (i < N_NODES) rowptr[i] = s[threadIdx.x] - v;  // exclusive
  if (threadIdx.x == 255) bsums[blockIdx.x] = s[255];
}

__global__ __launch_bounds__(512) void scan2_k(int* __restrict__ bsums) {
  __shared__ int s[512];
  int t = threadIdx.x;
  int v = (t < SCAN_BLOCKS) ? bsums[t] : 0;
  s[t] = v;
  __syncthreads();
  for (int off = 1; off < 512; off <<= 1) {
    int x = (t >= off) ? s[t - off] : 0;
    __syncthreads();
    s[t] += x;
    __syncthreads();
  }
  if (t < SCAN_BLOCKS) bsums[t] = s[t] - v;  // exclusive
}

__global__ __launch_bounds__(256) void scan3_k(int* __restrict__ rowptr,
                                               const int* __restrict__ bsums,
                                               int* __restrict__ cur) {
  int i = blockIdx.x * 256 + threadIdx.x;
  if (i < N_NODES) {
    int r = rowptr[i] + bsums[blockIdx.x];
    rowptr[i] = r;
    cur[i] = r;
  }
  if (i == 0) rowptr[N_NODES] = N_EDGES;
}

// csr entry: {src, e, dst, 0}
__global__ __launch_bounds__(256) void scatter_k(const int* __restrict__ ei,
                                                 int* __restrict__ cur,
                                                 uint4* __restrict__ csr) {
  int e = blockIdx.x * 256 + threadIdx.x;
  if (e >= N_EDGES) return;
  int d = ei[N_EDGES + e];
  int pos = atomicAdd(&cur[d], 1);
  csr[pos] = make_uint4((uint)ei[e], (uint)e, (uint)d, 0u);
}

// ---- ea_pack: bf16-pair pack of edge_attr in CSR order (built once) ----
// eab[p][16 dwords]: dword kk = bf16{ea[e][2kk], ea[e][2kk+1]}, e = csr[p].y
__global__ __launch_bounds__(256) void ea_pack(const float* __restrict__ ea,
                                               const uint4* __restrict__ csr,
                                               uint4* __restrict__ eab) {
  long long t = (long long)blockIdx.x * 256 + threadIdx.x;  // 8 floats/thread
  int p = (int)(t >> 2), q = (int)(t & 3);
  if (p >= N_EDGES) return;
  uint e = csr[p].y;
  const float4* er = (const float4*)(ea + (long long)e * 32 + q * 8);
  float4 a0 = er[0], a1 = er[1];
  uint4 pk;
  pk.x = pack_bf16_2(a0.x, a0.y);
  pk.y = pack_bf16_2(a0.z, a0.w);
  pk.z = pack_bf16_2(a1.x, a1.y);
  pk.w = pack_bf16_2(a1.z, a1.w);
  eab[(long long)p * 4 + q] = pk;
}

// ---------------- conv1 (channels=3) ----------------
__global__ __launch_bounds__(256) void conv1_edge(
    const float* __restrict__ x, const int* __restrict__ ei,
    const float* __restrict__ ea,
    const float* __restrict__ Wf, const float* __restrict__ bf,
    const float* __restrict__ Ws, const float* __restrict__ bs,
    float* __restrict__ agg1) {
  int e = blockIdx.x * 256 + threadIdx.x;
  if (e >= N_EDGES) return;
  int src = ei[e], dst = ei[N_EDGES + e];
  float z[38];
#pragma unroll
  for (int k = 0; k < 3; ++k) z[k] = x[dst * 3 + k];
#pragma unroll
  for (int k = 0; k < 3; ++k) z[3 + k] = x[src * 3 + k];
  const float4* er4 = (const float4*)(ea + (long long)e * 32);
#pragma unroll
  for (int k = 0; k < 8; ++k) {
    float4 v = er4[k];
    z[6 + 4 * k + 0] = v.x;
    z[6 + 4 * k + 1] = v.y;
    z[6 + 4 * k + 2] = v.z;
    z[6 + 4 * k + 3] = v.w;
  }
#pragma unroll
  for (int c = 0; c < 3; ++c) {
    float f = bf[c], s = bs[c];
#pragma unroll
    for (int k = 0; k < 38; ++k) {
      f = fmaf(z[k], Wf[k * 3 + c], f);
      s = fmaf(z[k], Ws[k * 3 + c], s);
    }
    atomicAdd(&agg1[dst * 3 + c], sigmoidf_(f) * softplusf_(s));
  }
}

// ---------------- projection: h = relu((x+agg1) @ Wp + bp) ----------------
__global__ __launch_bounds__(256) void proj_kernel(
    const float* __restrict__ x, const float* __restrict__ agg1,
    const float* __restrict__ Wp, const float* __restrict__ bp,
    float* __restrict__ h) {
  long long i = (long long)blockIdx.x * 256 + threadIdx.x;
  if (i >= (long long)N_NODES * HID) return;
  int n = (int)(i >> 7), j = (int)(i & 127);
  float v0 = x[n * 3 + 0] + agg1[n * 3 + 0];
  float v1 = x[n * 3 + 1] + agg1[n * 3 + 1];
  float v2 = x[n * 3 + 2] + agg1[n * 3 + 2];
  float acc = bp[j];
  acc = fmaf(v0, Wp[0 * HID + j], acc);
  acc = fmaf(v1, Wp[1 * HID + j], acc);
  acc = fmaf(v2, Wp[2 * HID + j], acc);
  h[i] = fmaxf(acc, 0.f);
}

#define BM 64
#define BK 32

// ---------------- node gates, packed {f,s} per channel ----------------
// Pb[node][256 dwords]: [0..127] = {f_dst+bf, s_dst+bs} per ch (biases
// folded here, once per edge via the dst gate); [128..255] = {f_src, s_src}
__global__ __launch_bounds__(256) void node_gemm2(
    const float* __restrict__ h, const float* __restrict__ Wf,
    const float* __restrict__ Ws, const float* __restrict__ bf,
    const float* __restrict__ bs, uint* __restrict__ Pb) {
  __shared__ float As[BK][BM + 4];
  __shared__ float BfS[BK][BM + 4];
  __shared__ float BsS[BK][BM + 4];
  int jblk = blockIdx.x;            // 0..3
  int part = jblk >> 1;             // 0 dst, 1 src
  int colbase = (jblk & 1) * 64;
  int rowoff = part * 128;
  int m0 = blockIdx.y * BM;
  int tid = threadIdx.x, tx = tid & 15, ty = tid >> 4;
  float accF[4][4] = {}, accS[4][4] = {};
  for (int k0 = 0; k0 < 128; k0 += BK) {
#pragma unroll
    for (int i = 0; i < 2; ++i) {
      int f = tid + i * 256;
      int r = f >> 3, c4 = (f & 7) * 4;
      float4 v = {0.f, 0.f, 0.f, 0.f};
      int row = m0 + r;
      if (row < N_NODES)
        v = *(const float4*)&h[(long long)row * 128 + k0 + c4];
      As[c4 + 0][r] = v.x; As[c4 + 1][r] = v.y;
      As[c4 + 2][r] = v.z; As[c4 + 3][r] = v.w;
    }
#pragma unroll
    for (int i = 0; i < 2; ++i) {
      int f = tid + i * 256;
      int r = f >> 4, c4 = (f & 15) * 4;
      *(float4*)&BfS[r][c4] =
          *(const float4*)&Wf[(long long)(k0 + r + rowoff) * 128 + colbase + c4];
      *(float4*)&BsS[r][c4] =
          *(const float4*)&Ws[(long long)(k0 + r + rowoff) * 128 + colbase + c4];
    }
    __syncthreads();
#pragma unroll
    for (int k = 0; k < BK; ++k) {
      float4 a = *(const float4*)&As[k][ty * 4];
      float4 bF = *(const float4*)&BfS[k][tx * 4];
      float4 bS = *(const float4*)&BsS[k][tx * 4];
      float av[4] = {a.x, a.y, a.z, a.w};
      float bFv[4] = {bF.x, bF.y, bF.z, bF.w};
      float bSv[4] = {bS.x, bS.y, bS.z, bS.w};
#pragma unroll
      for (int i = 0; i < 4; ++i)
#pragma unroll
        for (int j = 0; j < 4; ++j) {
          accF[i][j] = fmaf(av[i], bFv[j], accF[i][j]);
          accS[i][j] = fmaf(av[i], bSv[j], accS[i][j]);
        }
    }
    __syncthreads();
  }
  float fbias[4] = {0.f, 0.f, 0.f, 0.f}, sbias[4] = {0.f, 0.f, 0.f, 0.f};
  if (part == 0) {
#pragma unroll
    for (int j = 0; j < 4; ++j) {
      fbias[j] = bf[colbase + tx * 4 + j];
      sbias[j] = bs[colbase + tx * 4 + j];
    }
  }
#pragma unroll
  for (int i = 0; i < 4; ++i) {
    int row = m0 + ty * 4 + i;
    if (row < N_NODES) {
      uint4 o;
      o.x = pack_bf16_2(accF[i][0] + fbias[0], accS[i][0] + sbias[0]);
      o.y = pack_bf16_2(accF[i][1] + fbias[1], accS[i][1] + sbias[1]);
      o.z = pack_bf16_2(accF[i][2] + fbias[2], accS[i][2] + sbias[2]);
      o.w = pack_bf16_2(accF[i][3] + fbias[3], accS[i][3] + sbias[3]);
      *(uint4*)&Pb[(long long)row * 256 + part * 128 + colbase + tx * 4] = o;
    }
  }
}

// ---- w_prep: Btg[ch 0..255][16 dwords] = bf16{W[256+2k][c], W[256+2k+1][c]} ----
__global__ __launch_bounds__(256) void w_prep(const float* __restrict__ Wf,
                                              const float* __restrict__ Ws,
                                              uint* __restrict__ Btg) {
  int t = threadIdx.x;
  const float* W = (t < 128) ? Wf : Ws;
  int c = t & 127;
#pragma unroll
  for (int kk = 0; kk < 16; ++kk) {
    float a = W[(256 + 2 * kk) * 128 + c];
    float b = W[(256 + 2 * kk + 1) * 128 + c];
    Btg[t * 16 + kk] = pack_bf16_2(a, b);
  }
}

// ---- edge_msg: MFMA edge-gemm + gates + activations + LDS-accumulated
//      per-window aggregation; complete nodes flushed with plain RMW ----
#define EMSG_EB 64
#define LSTR 20  // LDS row stride in dwords (80B): b128-aligned, conflict-lite
#define CAP 16   // max tracked distinct dsts per window (typ ~5)
__global__ __launch_bounds__(256, 4) void edge_msg(
    const uint* __restrict__ Pb, const uint4* __restrict__ eab,
    const uint* __restrict__ Btg, const uint4* __restrict__ csr,
    const int* __restrict__ rowptr, float* __restrict__ h) {
  __shared__ uint Alds[EMSG_EB * LSTR];
  __shared__ uint Blds[256 * LSTR];
  __shared__ float accL[CAP * 128];
  __shared__ int dstL[64], srcL[64], liL[64];
  __shared__ int dlist[CAP], compL[CAP];
  __shared__ int nDistS;
  int tid = threadIdx.x;
  int j0 = blockIdx.x * EMSG_EB;
  // stage A: CSR-ordered pre-packed edge rows, straight 4KB copy
  {
    int r = tid >> 2, q = tid & 3;
    uint4 v = eab[(long long)j0 * 4 + tid];
    *(uint4*)&Alds[r * LSTR + q * 4] = v;
  }
  // stage B: weights
  {
    const uint4* s4 = (const uint4*)(Btg + tid * 16);
    uint4 v0 = s4[0], v1 = s4[1], v2 = s4[2], v3 = s4[3];
    uint* d = &Blds[tid * LSTR];
    *(uint4*)(d + 0) = v0; *(uint4*)(d + 4) = v1;
    *(uint4*)(d + 8) = v2; *(uint4*)(d + 12) = v3;
  }
  // zero the accumulator (2048 dwords)
#pragma unroll
  for (int i = 0; i < (CAP * 128) / 256; ++i) accL[tid + i * 256] = 0.f;
  // wave 0: dst/src lists, local-dst index, completeness
  if (tid < 64) {
    uint4 cj = csr[j0 + tid];
    int d = (int)cj.z;
    dstL[tid] = d;
    srcL[tid] = (int)cj.x;
    int dprev = __shfl_up(d, 1, 64);
    bool flag = (tid == 0) || (d != dprev);
    unsigned long long m = __ballot(flag);
    unsigned long long pre = (tid == 63) ? ~0ull : ((1ull << (tid + 1)) - 1);
    int li = __popcll(m & pre) - 1;
    liL[tid] = li;
    if (flag && li < CAP) {
      dlist[li] = d;
      int r0 = rowptr[d], r1 = rowptr[d + 1];
      compL[li] = ((r0 == j0 + tid) && (r1 <= j0 + EMSG_EB)) ? 1 : 0;
    }
    if (tid == 0) nDistS = __popcll(m);
  }
  __syncthreads();
  int wave = tid >> 6, lane = tid & 63;
  int c0w = wave * 32;  // 32 channels per wave
  int l15 = lane & 15, lq = lane >> 4;
  bf16x8 afr[4], bfr[4];
#pragma unroll
  for (int mt = 0; mt < 4; ++mt)
    afr[mt] = *(const bf16x8*)&Alds[(mt * 16 + l15) * LSTR + lq * 4];
  int chs0 = c0w + l15, chs1 = c0w + 16 + l15;
  bfr[0] = *(const bf16x8*)&Blds[chs0 * LSTR + lq * 4];
  bfr[1] = *(const bf16x8*)&Blds[chs1 * LSTR + lq * 4];
  bfr[2] = *(const bf16x8*)&Blds[(128 + chs0) * LSTR + lq * 4];
  bfr[3] = *(const bf16x8*)&Blds[(128 + chs1) * LSTR + lq * 4];
  f32x4 acc[4][4];
#pragma unroll
  for (int mt = 0; mt < 4; ++mt)
#pragma unroll
    for (int nt = 0; nt < 4; ++nt) {
      f32x4 z = {0.f, 0.f, 0.f, 0.f};
      acc[mt][nt] = __builtin_amdgcn_mfma_f32_16x16x32_bf16(afr[mt], bfr[nt], z, 0, 0, 0);
    }
  // epilogue: C layout col=lane&15 (ch), row=(lane>>4)*4+reg (edge).
  // run-reduce by local dst, accumulate into LDS (or global atomic if
  // the window overflowed CAP distinct dsts).
#pragma unroll
  for (int mt = 0; mt < 4; ++mt) {
    int o = mt * 16 + lq * 4;
    int dsts[4], lis[4];
#pragma unroll
    for (int reg = 0; reg < 4; ++reg) {
      dsts[reg] = dstL[o + reg];
      lis[reg] = liL[o + reg];
    }
#pragma unroll
    for (int cp = 0; cp < 2; ++cp) {
      int c = (cp ? chs1 : chs0);
      float mr[4];
#pragma unroll
      for (int reg = 0; reg < 4; ++reg) {
        uint gd = Pb[(long long)dsts[reg] * 256 + c];
        uint gs = Pb[(long long)srcL[o + reg] * 256 + 128 + c];
        float f = acc[mt][cp][reg] + bflo(gd) + bflo(gs);
        float s = acc[mt][2 + cp][reg] + bfhi(gd) + bfhi(gs);
        mr[reg] = sigmoidf_(f) * softplusf_(s);
      }
      float racc = mr[0];
      int cl = lis[0], cd = dsts[0];
#pragma unroll
      for (int reg = 1; reg < 4; ++reg) {
        if (lis[reg] == cl) {
          racc += mr[reg];
        } else {
          if (cl < CAP) atomicAdd(&accL[cl * 128 + c], racc);
          else atomicAdd(&h[(long long)cd * HID + c], racc);
          cl = lis[reg]; cd = dsts[reg]; racc = mr[reg];
        }
      }
      if (cl < CAP) atomicAdd(&accL[cl * 128 + c], racc);
      else atomicAdd(&h[(long long)cd * HID + c], racc);
    }
  }
  __syncthreads();
  // flush: complete nodes -> plain RMW + relu; straddlers -> global atomic
  int nD = nDistS;
  if (nD > CAP) nD = CAP;
  int c = tid & 127;
  for (int li = tid >> 7; li < nD; li += 2) {
    int d = dlist[li];
    float v = accL[li * 128 + c];
    float* hp = &h[(long long)d * HID + c];
    if (compL[li]) {
      *hp = fmaxf(*hp + v, 0.f);
    } else {
      atomicAdd(hp, v);
    }
  }
}

// ---- relu in place over h (idempotent on already-relu'd nodes) ----
__global__ __launch_bounds__(256) void relu_k(float* __restrict__ h) {
  const int total = N_NODES * HID / 4;
  for (int i = blockIdx.x * 256 + threadIdx.x; i < total; i += gridDim.x * 256) {
    float4 v = ((float4*)h)[i];
    v.x = fmaxf(v.x, 0.f); v.y = fmaxf(v.y, 0.f);
    v.z = fmaxf(v.z, 0.f); v.w = fmaxf(v.w, 0.f);
    ((float4*)h)[i] = v;
  }
}

// -------- segmented mean pool (batch sorted) --------
#define POOL_NODES 128
__global__ __launch_bounds__(128) void pool2(
    const float* __restrict__ h, const int* __restrict__ batch,
    float* __restrict__ sums, float* __restrict__ cnts) {
  int n0 = blockIdx.x * POOL_NODES;
  if (n0 >= N_NODES) return;
  int t = threadIdx.x;
  int nEnd = n0 + POOL_NODES;
  if (nEnd > N_NODES) nEnd = N_NODES;
  float acc = 0.f;
  int bcur = batch[n0];
  int cnt = 0;
  for (int n = n0; n < nEnd; ++n) {
    int b = batch[n];
    if (b != bcur) {
      atomicAdd(&sums[bcur * HID + t], acc);
      if (t == 0) atomicAdd(&cnts[bcur], (float)cnt);
      acc = 0.f; cnt = 0; bcur = b;
    }
    acc += h[(long long)n * HID + t];
    ++cnt;
  }
  atomicAdd(&sums[bcur * HID + t], acc);
  if (t == 0) atomicAdd(&cnts[bcur], (float)cnt);
}

// ---------------- graph MLP ----------------
__global__ __launch_bounds__(128) void mlpA(
    const float* __restrict__ sums, const float* __restrict__ cnts,
    const float* __restrict__ W1, const float* __restrict__ b1,
    float* __restrict__ g) {
  __shared__ float pl[HID];
  int gr = blockIdx.x, j = threadIdx.x;
  float cnt = fmaxf(cnts[gr], 1.f);
  pl[j] = sums[gr * HID + j] / cnt;
  __syncthreads();
  float acc = b1[j];
#pragma unroll 8
  for (int k = 0; k < HID; ++k) acc = fmaf(pl[k], W1[k * HID + j], acc);
  g[gr * HID + j] = fmaxf(acc, 0.f);
}

__global__ __launch_bounds__(256) void mlpB(
    const float* __restrict__ g, const float* __restrict__ W2,
    const float* __restrict__ b2, float* __restrict__ out) {
  int t = threadIdx.x;
  if (t >= 64 * 3) return;
  int gr = t / 3, o = t % 3;
  float acc = b2[o];
#pragma unroll 8
  for (int k = 0; k < HID; ++k) acc = fmaf(g[gr * HID + k], W2[k * 3 + o], acc);
  out[t] = acc;
}

extern "C" void kernel_launch(void* const* d_in, const int* in_sizes, int n_in,
                              void* d_out, int out_size, void* d_ws, size_t ws_size,
                              hipStream_t stream) {
  const float* x   = (const float*)d_in[0];
  const int*   ei  = (const int*)d_in[1];
  const float* ea  = (const float*)d_in[2];
  const int*   bat = (const int*)d_in[3];
  const float* Wf1 = (const float*)d_in[4];
  const float* bf1 = (const float*)d_in[5];
  const float* Ws1 = (const float*)d_in[6];
  const float* bs1 = (const float*)d_in[7];
  const float* Wp  = (const float*)d_in[8];
  const float* bp  = (const float*)d_in[9];
  const float* Wf2 = (const float*)d_in[10];
  const float* bf2 = (const float*)d_in[11];
  const float* Ws2 = (const float*)d_in[12];
  const float* bs2 = (const float*)d_in[13];
  const float* Wf3 = (const float*)d_in[14];
  const float* bf3 = (const float*)d_in[15];
  const float* Ws3 = (const float*)d_in[16];
  const float* bs3 = (const float*)d_in[17];
  const float* W1  = (const float*)d_in[18];
  const float* b1  = (const float*)d_in[19];
  const float* W2  = (const float*)d_in[20];
  const float* b2  = (const float*)d_in[21];
  float* out = (float*)d_out;

  char* w = (char*)d_ws;
  size_t off = 0;
  auto alloc = [&](size_t bytes) {
    void* p = w + off;
    off += (bytes + 255) & ~(size_t)255;
    return p;
  };
  int*   deg    = (int*)alloc((size_t)N_NODES * 4);
  int*   rowptr = (int*)alloc((size_t)(N_NODES + 1) * 4);
  int*   cur    = (int*)alloc((size_t)N_NODES * 4);
  int*   bsums  = (int*)alloc((size_t)512 * 4);
  uint4* csr    = (uint4*)alloc((size_t)N_EDGES * 16);       // 25.6 MB
  float* agg1   = (float*)alloc((size_t)N_NODES * 3 * 4);    // 1.2 MB
  float* h      = (float*)alloc((size_t)N_NODES * HID * 4);  // 51.2 MB
  uint*  Pb     = (uint*)alloc((size_t)N_NODES * 256 * 4);   // 102.4 MB
  uint4* eab    = (uint4*)alloc((size_t)N_EDGES * 64);       // 102.4 MB
  float* sums   = (float*)alloc((size_t)64 * HID * 4);
  float* cnts   = (float*)alloc((size_t)64 * 4);
  float* g      = (float*)alloc((size_t)64 * HID * 4);
  uint*  Btg    = (uint*)alloc((size_t)256 * 16 * 4);        // 16 KB
  (void)ws_size;  // total ~285 MB

  // ---- CSR build ----
  hipMemsetAsync(deg, 0, (size_t)N_NODES * 4, stream);
  hist_k<<<(N_EDGES + 255) / 256, 256, 0, stream>>>(ei, deg);
  scan1_k<<<SCAN_BLOCKS, 256, 0, stream>>>(deg, rowptr, bsums);
  scan2_k<<<1, 512, 0, stream>>>(bsums);
  scan3_k<<<SCAN_BLOCKS, 256, 0, stream>>>(rowptr, bsums, cur);
  scatter_k<<<(N_EDGES + 255) / 256, 256, 0, stream>>>(ei, cur, csr);
  ea_pack<<<(N_EDGES * 4 + 255) / 256, 256, 0, stream>>>(ea, csr, eab);

  // ---- conv1 ----
  hipMemsetAsync(agg1, 0, (size_t)N_NODES * 3 * 4, stream);
  conv1_edge<<<(N_EDGES + 255) / 256, 256, 0, stream>>>(x, ei, ea, Wf1, bf1, Ws1, bs1, agg1);
  proj_kernel<<<(N_NODES * HID + 255) / 256, 256, 0, stream>>>(x, agg1, Wp, bp, h);

  dim3 ngrid2(4, (N_NODES + BM - 1) / BM);
  int eblocks = N_EDGES / EMSG_EB;  // 25000, exact

  // ---- conv2: h += agg (LDS-accumulated), relu ----
  node_gemm2<<<ngrid2, 256, 0, stream>>>(h, Wf2, Ws2, bf2, bs2, Pb);
  w_prep<<<1, 256, 0, stream>>>(Wf2, Ws2, Btg);
  edge_msg<<<eblocks, 256, 0, stream>>>(Pb, eab, Btg, csr, rowptr, h);
  relu_k<<<4096, 256, 0, stream>>>(h);

  // ---- conv3 ----
  node_gemm2<<<ngrid2, 256, 0, stream>>>(h, Wf3, Ws3, bf3, bs3, Pb);
  w_prep<<<1, 256, 0, stream>>>(Wf3, Ws3, Btg);
  edge_msg<<<eblocks, 256, 0, stream>>>(Pb, eab, Btg, csr, rowptr, h);
  relu_k<<<4096, 256, 0, stream>>>(h);

  // ---- pool + MLP ----
  hipMemsetAsync(sums, 0, (size_t)(64 * HID + 64) * 4, stream);
  pool2<<<(N_NODES + POOL_NODES - 1) / POOL_NODES, POOL_NODES, 0, stream>>>(h, bat, sums, cnts);
  mlpA<<<64, 128, 0, stream>>>(sums, cnts, W1, b1, g);
  mlpB<<<1, 256, 0, stream>>>(g, W2, b2, out);
}